// Round 1
// baseline (272.750 us; speedup 1.0000x reference)
//
#include <hip/hip_runtime.h>
#include <hip/hip_bf16.h>

#define EMBED 128
#define TSTEPS 128
#define NBATCH 32
#define VDIM 50257
#define MROWS 4096            // NBATCH * TSTEPS
#define NCHUNKS 3142          // ceil(VDIM/16)
#define GRIDX 64
#define CHUNKS_PB 50          // ceil(NCHUNKS/GRIDX)

static constexpr float LOG2E = 1.4426950408889634f;
static constexpr float LN2   = 0.6931471805599453f;

__device__ __forceinline__ float fast_exp2(float x) {
#if __has_builtin(__builtin_amdgcn_exp2f)
    return __builtin_amdgcn_exp2f(x);
#else
    return exp2f(x);
#endif
}
__device__ __forceinline__ float fast_log2(float x) {
#if __has_builtin(__builtin_amdgcn_logf)
    return __builtin_amdgcn_logf(x);
#else
    return log2f(x);
#endif
}
__device__ __forceinline__ unsigned short f2bf_raw(float f) {
    __hip_bfloat16 h = __float2bfloat16(f);
    union { __hip_bfloat16 b; unsigned short u; } cvt;
    cvt.b = h;
    return cvt.u;
}

// ---------------------------------------------------------------------------
// K0: convert Wv fp32 -> bf16 (row-major [V][E] preserved)
// ---------------------------------------------------------------------------
__global__ __launch_bounds__(256) void conv_wv_kernel(const float* __restrict__ Wv,
                                                      unsigned short* __restrict__ Wvb,
                                                      int n4) {
    int i = blockIdx.x * blockDim.x + threadIdx.x;
    if (i >= n4) return;
    float4 v = reinterpret_cast<const float4*>(Wv)[i];
    ushort4 o;
    o.x = f2bf_raw(v.x); o.y = f2bf_raw(v.y); o.z = f2bf_raw(v.z); o.w = f2bf_raw(v.w);
    reinterpret_cast<ushort4*>(Wvb)[i] = o;
}

// ---------------------------------------------------------------------------
// K1: the sequential scan. One block per batch element (32 independent
// chains). 256 threads: e = tid&127 (output element), h = tid>>7 (k-half).
// Each thread caches its half of Wt row e in 16 float4 VGPRs; z lives in LDS.
// Emits zs (pre-update z) in fp32 (for exact target dot) and bf16*log2e
// (A-matrix of the big GEMM).
// ---------------------------------------------------------------------------
__global__ __launch_bounds__(256) void scan_kernel(const int* __restrict__ zi,
                                                   const float* __restrict__ latent,
                                                   const float* __restrict__ Wt,
                                                   const float* __restrict__ bt,
                                                   float* __restrict__ zs_f32,
                                                   unsigned short* __restrict__ zsb) {
    __shared__ float z_lds[EMBED];
    __shared__ float partial[EMBED];
    const int b = blockIdx.x;
    const int e = threadIdx.x & 127;
    const int h = threadIdx.x >> 7;

    // cache Wt[e][h*64 .. h*64+63] in registers
    float4 wrow[16];
    const float4* wt4 = reinterpret_cast<const float4*>(Wt + e * EMBED + h * 64);
#pragma unroll
    for (int i = 0; i < 16; i++) wrow[i] = wt4[i];
    const float bte = bt[e];

    if (h == 0) z_lds[e] = latent[zi[b] * EMBED + e];
    __syncthreads();

    for (int t = 0; t < TSTEPS; t++) {
        const float zc = z_lds[e];
        const long row = (long)b * TSTEPS + t;
        if (h == 0) zs_f32[row * EMBED + e] = zc;           // emit pre-update z
        else        zsb[row * EMBED + e] = f2bf_raw(zc * LOG2E);

        // half-dot: sum_k z[k] * Wt[e][k], k in [h*64, h*64+64)
        const float4* z4 = reinterpret_cast<const float4*>(z_lds + h * 64);
        float4 acc = {0.f, 0.f, 0.f, 0.f};
#pragma unroll
        for (int i = 0; i < 16; i++) {
            float4 zv = z4[i];          // LDS broadcast (wave-uniform address)
            acc.x += zv.x * wrow[i].x;
            acc.y += zv.y * wrow[i].y;
            acc.z += zv.z * wrow[i].z;
            acc.w += zv.w * wrow[i].w;
        }
        float s = acc.x + acc.y + acc.z + acc.w;
        if (h == 1) partial[e] = s;
        __syncthreads();
        if (h == 0) {
            float znew = tanhf(zc + s + partial[e] + bte);
            z_lds[e] = znew;
        }
        __syncthreads();
    }
}

// ---------------------------------------------------------------------------
// K2: fused GEMM + sum-of-exp2.  A = zsb [4096 x 128] (bf16, pre-scaled by
// log2e), B = Wvb [50257 x 128] (bf16).  Each block: 4 waves x 64 rows =
// 256 rows, a V-slice of CHUNKS_PB 16-col chunks.  A-fragments held in
// registers for the whole slice.  C init = bv*log2e (folds the bias add
// into the MFMA).  Per-row partial sumexp -> shfl reduce -> one atomicAdd.
// mfma_f32_16x16x32_bf16 layouts (HW-verified, guide §3):
//   A: lane holds A[m=lane&15][k=(lane>>4)*8 + j], j=0..7
//   B: lane holds B[n=lane&15][k=(lane>>4)*8 + j]   (row-major [n][k] = B^T)
//   D: lane holds D[row=(lane>>4)*4 + r][col=lane&15], r=0..3
// ---------------------------------------------------------------------------
typedef __attribute__((ext_vector_type(8))) short bfrag;
typedef __attribute__((ext_vector_type(4))) float f32x4;

__global__ __launch_bounds__(256, 4) void gemm_lse_kernel(const unsigned short* __restrict__ zsb,
                                                          const unsigned short* __restrict__ Wvb,
                                                          const float* __restrict__ bv,
                                                          float* __restrict__ S) {
    const int lane  = threadIdx.x & 63;
    const int wave  = threadIdx.x >> 6;
    const int col16 = lane & 15;
    const int quad  = lane >> 4;
    const int mbase = blockIdx.y * 256 + wave * 64;

    // A fragments: 4 M-subtiles x 4 K-chunks, register resident (64 VGPRs)
    bfrag a[4][4];
    const short* zss = reinterpret_cast<const short*>(zsb);
#pragma unroll
    for (int s = 0; s < 4; s++)
#pragma unroll
        for (int c = 0; c < 4; c++) {
            const short* p = zss + (long)(mbase + s * 16 + col16) * EMBED + c * 32 + quad * 8;
            a[s][c] = *reinterpret_cast<const bfrag*>(p);
        }

    float sums[16];
#pragma unroll
    for (int i = 0; i < 16; i++) sums[i] = 0.f;

    const int chunk0 = blockIdx.x * CHUNKS_PB;
    const int chunk1 = min(chunk0 + CHUNKS_PB, NCHUNKS);
    const short* wvs = reinterpret_cast<const short*>(Wvb);

    for (int nc = chunk0; nc < chunk1; nc++) {
        const int col  = nc * 16 + col16;
        const int colc = min(col, VDIM - 1);
        const float binit = (col < VDIM) ? bv[colc] * LOG2E : -1e30f;

        bfrag bf[4];
#pragma unroll
        for (int c = 0; c < 4; c++) {
            const short* p = wvs + (long)colc * EMBED + c * 32 + quad * 8;
            bf[c] = *reinterpret_cast<const bfrag*>(p);
        }

#pragma unroll
        for (int s = 0; s < 4; s++) {
            f32x4 d = {binit, binit, binit, binit};
#pragma unroll
            for (int c = 0; c < 4; c++)
                d = __builtin_amdgcn_mfma_f32_16x16x32_bf16(a[s][c], bf[c], d, 0, 0, 0);
#pragma unroll
            for (int r = 0; r < 4; r++)
                sums[s * 4 + r] += fast_exp2(d[r]);
        }
    }

    // reduce partial sums over the 16 columns (lanes within each quad group)
#pragma unroll
    for (int s = 0; s < 4; s++) {
#pragma unroll
        for (int r = 0; r < 4; r++) {
            float v = sums[s * 4 + r];
            v += __shfl_xor(v, 1);
            v += __shfl_xor(v, 2);
            v += __shfl_xor(v, 4);
            v += __shfl_xor(v, 8);
            if (col16 == 0)
                atomicAdd(&S[mbase + s * 16 + quad * 4 + r], v);
        }
    }
}

// ---------------------------------------------------------------------------
// K3: yp[row] = (zs[row] . Wv[y[row]] + bv[y[row]]) - ln2 * log2(S[row])
// Target dot in full fp32 (the error-dominant term).  One wave per row.
// ---------------------------------------------------------------------------
__global__ __launch_bounds__(256) void tail_kernel(const float* __restrict__ zs,
                                                   const float* __restrict__ Wv,
                                                   const float* __restrict__ bv,
                                                   const int* __restrict__ y,
                                                   const float* __restrict__ S,
                                                   float* __restrict__ out) {
    const int row  = blockIdx.x * 4 + (threadIdx.x >> 6);
    const int lane = threadIdx.x & 63;
    const int yv = y[row];
    const float* zr = zs + (long)row * EMBED;
    const float* wr = Wv + (long)yv * EMBED;
    float v = zr[lane] * wr[lane] + zr[lane + 64] * wr[lane + 64];
    v += __shfl_xor(v, 32);
    v += __shfl_xor(v, 16);
    v += __shfl_xor(v, 8);
    v += __shfl_xor(v, 4);
    v += __shfl_xor(v, 2);
    v += __shfl_xor(v, 1);
    if (lane == 0)
        out[row] = v + bv[yv] - LN2 * fast_log2(S[row]);
}

// ---------------------------------------------------------------------------
extern "C" void kernel_launch(void* const* d_in, const int* in_sizes, int n_in,
                              void* d_out, int out_size, void* d_ws, size_t ws_size,
                              hipStream_t stream) {
    const int*   zi     = (const int*)d_in[0];
    const int*   y      = (const int*)d_in[1];
    const float* latent = (const float*)d_in[2];
    const float* Wt     = (const float*)d_in[3];
    const float* bt     = (const float*)d_in[4];
    const float* Wv     = (const float*)d_in[5];
    const float* bv     = (const float*)d_in[6];
    float* out = (float*)d_out;

    char* ws = (char*)d_ws;
    // workspace layout (~16.05 MB total):
    float*          zs_f32 = (float*)ws;                              // 2 MB
    unsigned short* zsb    = (unsigned short*)(ws + (2u << 20));      // 1 MB
    unsigned short* wvb    = (unsigned short*)(ws + (3u << 20));      // 12.27 MB
    float*          S      = (float*)(ws + (16u << 20));              // 16 KB

    hipMemsetAsync(S, 0, MROWS * sizeof(float), stream);

    const int n4 = (VDIM * EMBED) / 4;
    conv_wv_kernel<<<(n4 + 255) / 256, 256, 0, stream>>>(Wv, wvb, n4);

    scan_kernel<<<NBATCH, 256, 0, stream>>>(zi, latent, Wt, bt, zs_f32, zsb);

    gemm_lse_kernel<<<dim3(GRIDX, MROWS / 256), 256, 0, stream>>>(zsb, wvb, bv, S);

    tail_kernel<<<MROWS / 4, 256, 0, stream>>>(zs_f32, Wv, bv, y, S, out);
}